// Round 6
// baseline (200.143 us; speedup 1.0000x reference)
//
#include <hip/hip_runtime.h>
#include <hip/hip_bf16.h>

#define B_      8
#define N_      2000
#define H_      128
#define HEADS_  4
#define INF_    160
#define DH_     32
#define BN_     8
#define HOR_    24
#define ALPHA_  0.2f
#define EPS_    1e-5f
#define LOG2E_  1.4426950408889634f

typedef __bf16 bf16x4 __attribute__((ext_vector_type(4)));
typedef __bf16 bf16x8 __attribute__((ext_vector_type(8)));
typedef float  f32x16 __attribute__((ext_vector_type(16)));
typedef float  f32x2  __attribute__((ext_vector_type(2)));

__device__ __forceinline__ float wredsum(float v) {
#pragma unroll
    for (int m = 1; m <= 32; m <<= 1) v += __shfl_xor(v, m, 64);
    return v;
}

// ---------------- Kernel P: adjacency bitmasks (ballot) + W_gat pack (blocks<80) ------
__global__ __launch_bounds__(256) void k_pack(const int* __restrict__ adj,
                                              unsigned int* __restrict__ adjp,
                                              const float* __restrict__ W_gat,
                                              __bf16* __restrict__ Wpk) {
    int t = threadIdx.x;
    if (blockIdx.x < 80) {                      // fused wprep: 80*256 = 20480 elems
        int idx = blockIdx.x * 256 + t;
        int h = idx / 5120, rem = idx % 5120;
        int s = rem / 512, q = rem % 512;
        int l = q >> 3, j = q & 7;
        int k = s * 16 + (l >> 5) * 8 + j;
        int o = l & 31;
        float v = W_gat[(h * INF_ + k) * 32 + o];
        __bf16 hi = (__bf16)v;
        Wpk[idx] = hi;
        Wpk[idx + 20480] = (__bf16)(v - (float)hi);
    }
    int lane = t & 63, w = t >> 6;
    int n = blockIdx.x * 4 + w;                 // 500 blocks x 4 waves = 2000 rows
    const int* row = adj + (size_t)n * N_;
#pragma unroll 4
    for (int it = 0; it < 32; it++) {
        int base = it * 64 + lane;
        int pred = (base < N_) ? (row[base] != 0) : 0;
        unsigned long long mask = __ballot(pred);
        if (lane == 0) {
            adjp[n * 64 + it * 2]     = (unsigned int)mask;
            adjp[n * 64 + it * 2 + 1] = (unsigned int)(mask >> 32);
        }
    }
}

// ---------------- Kernel WH: split-bf16 MFMA projection, fused ssd/ef + transpose -----
__global__ __launch_bounds__(256) void k_wh(const float* __restrict__ x,
                                            const float* __restrict__ loc_emb,
                                            const __bf16* __restrict__ Wpk,
                                            const float* __restrict__ a_src,
                                            const float* __restrict__ a_dst,
                                            __bf16* __restrict__ WhT,
                                            float2* __restrict__ Etab,
                                            float2* __restrict__ Ftab) {
    __shared__ __bf16 xhi[32][164];
    __shared__ __bf16 xlo[32][164];              // reused as transpose buffer later
    int t = threadIdx.x;
    int g0 = blockIdx.x * 32;
#pragma unroll
    for (int it = 0; it < 5; it++) {
        int idx = it * 256 + t;
        int r = idx / 40, c4 = idx % 40;
        int i4 = c4 * 4;
        float4 v;
        if (i4 < H_) {
            v = *(const float4*)&x[(size_t)(g0 + r) * H_ + i4];
        } else {
            int n = (g0 + r) % N_;
            v = *(const float4*)&loc_emb[n * 32 + (i4 - H_)];
        }
        bf16x4 h4, l4;
        h4[0] = (__bf16)v.x; l4[0] = (__bf16)(v.x - (float)h4[0]);
        h4[1] = (__bf16)v.y; l4[1] = (__bf16)(v.y - (float)h4[1]);
        h4[2] = (__bf16)v.z; l4[2] = (__bf16)(v.z - (float)h4[2]);
        h4[3] = (__bf16)v.w; l4[3] = (__bf16)(v.w - (float)h4[3]);
        *(bf16x4*)&xhi[r][i4] = h4;
        *(bf16x4*)&xlo[r][i4] = l4;
    }
    __syncthreads();

    int lane = t & 63, w = t >> 6;               // w = head
    int ln = lane & 31, grp = lane >> 5;
    f32x16 acc;
#pragma unroll
    for (int r = 0; r < 16; r++) acc[r] = 0.0f;

    for (int s = 0; s < 10; s++) {
        int off = s * 16 + grp * 8;
        bf16x4 a0 = *(const bf16x4*)&xhi[ln][off];
        bf16x4 a1 = *(const bf16x4*)&xhi[ln][off + 4];
        bf16x4 c0 = *(const bf16x4*)&xlo[ln][off];
        bf16x4 c1 = *(const bf16x4*)&xlo[ln][off + 4];
        bf16x8 ahi, alo;
#pragma unroll
        for (int q = 0; q < 4; q++) {
            ahi[q] = a0[q]; ahi[q + 4] = a1[q];
            alo[q] = c0[q]; alo[q + 4] = c1[q];
        }
        const __bf16* wp = Wpk + ((w * 10 + s) * 64 + lane) * 8;
        bf16x8 bhi = *(const bf16x8*)wp;
        bf16x8 blo = *(const bf16x8*)(wp + 20480);
        acc = __builtin_amdgcn_mfma_f32_32x32x16_bf16(ahi, bhi, acc, 0, 0, 0);
        acc = __builtin_amdgcn_mfma_f32_32x32x16_bf16(ahi, blo, acc, 0, 0, 0);
        acc = __builtin_amdgcn_mfma_f32_32x32x16_bf16(alo, bhi, acc, 0, 0, 0);
    }

    // ---- fused s_src/s_dst: reduce acc over cols (32 lanes of each half) ----
    float as = a_src[w * 32 + ln];
    float ad = a_dst[w * 32 + ln];
#pragma unroll
    for (int r = 0; r < 16; r++) {
        float ssv = acc[r] * as;
        float sdv = acc[r] * ad;
#pragma unroll
        for (int m = 1; m <= 16; m <<= 1) {
            ssv += __shfl_xor(ssv, m, 64);
            sdv += __shfl_xor(sdv, m, 64);
        }
        if (ln == 0) {
            int nr = (r & 3) + 8 * (r >> 2) + 4 * grp;
            int g = g0 + nr;
            int b = g / N_, n = g - b * N_;
            size_t idx = (size_t)(b * HEADS_ + w) * N_ + n;
            float sl = ssv * LOG2E_, dl = sdv * LOG2E_;
            Etab[idx] = make_float2(exp2f(sl), exp2f(0.2f * sl));
            Ftab[idx] = make_float2(exp2f(dl), exp2f(0.2f * dl));
        }
    }

    // ---- fused transpose -> WhT[bh][o][m] (reuse xlo as scratch) ----
    __syncthreads();                             // all waves done reading xhi/xlo
    __bf16 (*T)[34] = (__bf16(*)[34])((char*)&xlo[0][0] + w * 2176);  // [32 o][34]
#pragma unroll
    for (int r = 0; r < 16; r++) {
        int nr = (r & 3) + 8 * (r >> 2) + 4 * grp;
        T[ln][nr] = (__bf16)acc[r];
    }
    __syncthreads();
#pragma unroll
    for (int half = 0; half < 2; half++) {
        int j = grp * 16 + half * 8;             // 8 local rows
        int g = g0 + j;
        int b = g / N_, n = g - b * N_;
        if (n <= N_ - 8) {                       // no batch crossing in chunk
            uint4 d;
            d.x = *(const unsigned int*)&T[ln][j];
            d.y = *(const unsigned int*)&T[ln][j + 2];
            d.z = *(const unsigned int*)&T[ln][j + 4];
            d.w = *(const unsigned int*)&T[ln][j + 6];
            *(uint4*)(WhT + ((size_t)(b * HEADS_ + w) * 32 + ln) * 2048 + n) = d;
        } else {
            for (int i = 0; i < 8; i++) {
                int gg = g + i; int b2 = gg / N_, n2 = gg - b2 * N_;
                WhT[((size_t)(b2 * HEADS_ + w) * 32 + ln) * 2048 + n2] = T[ln][j + i];
            }
        }
    }
}

// ---------------- Kernel B: masked attention, packed-math scores + dual MFMA ----------
// grid (16 tiles x 32 bh) x 256 thr. Each wave owns 32 rows and sweeps ALL m.
// No combine stage, one barrier, LDS = fl only -> high occupancy.
__global__ __launch_bounds__(256, 6) void k_attn(const __bf16* __restrict__ WhT,
                                                 const float2* __restrict__ Etab,
                                                 const float2* __restrict__ Ftab,
                                                 const unsigned int* __restrict__ adjp,
                                                 float* __restrict__ h_prime) {
    __shared__ float2 fl[2048];                  // 16 KB (f1,f5) per m

    int t = threadIdx.x;
    int tile = blockIdx.x;                       // 0..15
    int bh = blockIdx.y;                         // 0..31
    int w = t >> 6, lane = t & 63;
    int ln = lane & 31, grp = lane >> 5;

    {
        const float4* Fb4 = (const float4*)(Ftab + (size_t)bh * N_);
        float4* fl4 = (float4*)fl;
        for (int i = t; i < 1024; i += 256)
            fl4[i] = (i < 1000) ? Fb4[i] : make_float4(0.f, 0.f, 0.f, 0.f);
    }
    int row = tile * 128 + w * 32 + ln;
    int rclamp = min(row, N_ - 1);
    float2 ee = Etab[(size_t)bh * N_ + rclamp];
    f32x2 ee2 = {ee.x, ee.y};
    const unsigned int* arow = adjp + (size_t)rclamp * 64;
    const __bf16* bbase = WhT + ((size_t)bh * 32 + ln) * 2048;

    f32x16 acc, acc2;
#pragma unroll
    for (int r = 0; r < 16; r++) { acc[r] = 0.0f; acc2[r] = 0.0f; }
    bf16x8 ones;
#pragma unroll
    for (int q = 0; q < 8; q++) ones[q] = (__bf16)1.0f;

    __syncthreads();

    for (int c = 0; c < 32; c++) {
        int m0 = c * 64;
        uint2 aw = *(const uint2*)&arow[c * 2];
        bf16x8 bfr[4];
#pragma unroll
        for (int s = 0; s < 4; s++)
            bfr[s] = *(const bf16x8*)&bbase[m0 + s * 16 + grp * 8];
#pragma unroll
        for (int s = 0; s < 4; s++) {
            int mo = m0 + s * 16 + grp * 8;
            unsigned int word = (s < 2) ? aw.x : aw.y;
            unsigned int mbyte = (word >> ((s & 1) * 16 + grp * 8)) & 0xffu;
            const float4* flp = (const float4*)&fl[mo];
            unsigned int au[4];
#pragma unroll
            for (int p = 0; p < 4; p++) {
                float4 fq = flp[p];              // (f1,f5, f1',f5') broadcast read
                f32x2 pa = f32x2{fq.x, fq.y} * ee2;
                f32x2 pb = f32x2{fq.z, fq.w} * ee2;
                float p0 = fmaxf(pa.x, pa.y);
                float p1 = fmaxf(pb.x, pb.y);
                p0 = ((mbyte >> (2 * p)) & 1u) ? p0 : 0.0f;
                p1 = ((mbyte >> (2 * p + 1)) & 1u) ? p1 : 0.0f;
                unsigned int d;
                asm("v_cvt_pk_bf16_f32 %0, %1, %2" : "=v"(d) : "v"(p0), "v"(p1));
                au[p] = d;
            }
            union { uint4 u; bf16x8 b; } cvt;
            cvt.u = make_uint4(au[0], au[1], au[2], au[3]);
            acc  = __builtin_amdgcn_mfma_f32_32x32x16_bf16(cvt.b, bfr[s], acc, 0, 0, 0);
            acc2 = __builtin_amdgcn_mfma_f32_32x32x16_bf16(cvt.b, ones,   acc2, 0, 0, 0);
        }
    }

    // ---- direct per-wave epilogue (no combine) ----
    int bq = bh >> 2, hh = bh & 3;
#pragma unroll
    for (int r = 0; r < 16; r++) {
        int nr = (r & 3) + 8 * (r >> 2) + 4 * grp;
        int n = tile * 128 + w * 32 + nr;
        if (n < N_) {
            h_prime[((size_t)(bq * N_ + n)) * H_ + hh * 32 + ln] = acc[r] / acc2[r];
        }
    }
}

// ---------------- Kernel C: LN + residual + LN + MLP head ----------------
__global__ __launch_bounds__(256) void k_head(const float* __restrict__ h_prime,
        const float* __restrict__ x, const float* __restrict__ last_step,
        const float* __restrict__ ln_gat_g, const float* __restrict__ ln_gat_b,
        const float* __restrict__ ln_g, const float* __restrict__ ln_b,
        const float* __restrict__ w_low, const float* __restrict__ b_low,
        const float* __restrict__ ln_bn_g, const float* __restrict__ ln_bn_b,
        const float* __restrict__ w_high, const float* __restrict__ b_high,
        const float* __restrict__ w_g1, const float* __restrict__ b_g1,
        const float* __restrict__ w_g2, const float* __restrict__ b_g2,
        float* __restrict__ out) {
    __shared__ float hsh[4][128];
    __shared__ float xms[4][8], sgs[4][8];
    int t = threadIdx.x;
    int w = t >> 6, lane = t & 63;
    int g = blockIdx.x * 4 + w;

    float2 hp = *(const float2*)&h_prime[(size_t)g * H_ + lane * 2];
    float2 xr = *(const float2*)&x[(size_t)g * H_ + lane * 2];

    float mean = wredsum(hp.x + hp.y) * (1.f / H_);
    float d0 = hp.x - mean, d1 = hp.y - mean;
    float var = wredsum(d0 * d0 + d1 * d1) * (1.f / H_);
    float rs = rsqrtf(var + EPS_);
    float2 gg = *(const float2*)&ln_gat_g[lane * 2];
    float2 gb = *(const float2*)&ln_gat_b[lane * 2];
    float a0 = d0 * rs * gg.x + gb.x + xr.x;
    float a1 = d1 * rs * gg.y + gb.y + xr.y;

    float mean2 = wredsum(a0 + a1) * (1.f / H_);
    float e0 = a0 - mean2, e1 = a1 - mean2;
    float var2 = wredsum(e0 * e0 + e1 * e1) * (1.f / H_);
    float rs2 = rsqrtf(var2 + EPS_);
    float2 g2 = *(const float2*)&ln_g[lane * 2];
    float2 b2 = *(const float2*)&ln_b[lane * 2];
    float h0 = e0 * rs2 * g2.x + b2.x;
    float h1 = e1 * rs2 * g2.y + b2.y;

    *(float2*)&hsh[w][2 * lane] = make_float2(h0, h1);
    __syncthreads();

    int j = lane & 7, i16 = lane >> 3;
    float xa = 0.f, ga = 0.f;
#pragma unroll
    for (int q = 0; q < 16; q++) {
        int qq = (q + 2 * i16) & 15;
        int i = i16 * 16 + qq;
        float hv = hsh[w][i];
        xa = fmaf(hv, w_low[i * BN_ + j], xa);
        ga = fmaf(hv, w_g1[i * BN_ + j], ga);
    }
#pragma unroll
    for (int m = 8; m <= 32; m <<= 1) {
        xa += __shfl_xor(xa, m, 64);
        ga += __shfl_xor(ga, m, 64);
    }
    xa += b_low[j];

    float mb = xa;
#pragma unroll
    for (int m = 1; m <= 4; m <<= 1) mb += __shfl_xor(mb, m, 64);
    mb *= (1.f / BN_);
    float db = xa - mb;
    float vb = db * db;
#pragma unroll
    for (int m = 1; m <= 4; m <<= 1) vb += __shfl_xor(vb, m, 64);
    vb *= (1.f / BN_);
    float rb = rsqrtf(vb + EPS_);
    float v = db * rb * ln_bn_g[j] + ln_bn_b[j];
    float xm = v / (1.f + __expf(-v));
    float u = ga + b_g1[j];
    float sg = u / (1.f + __expf(-u));
    if (lane < 8) { xms[w][lane] = xm; sgs[w][lane] = sg; }
    __syncthreads();

    if (lane < HOR_) {
        float ip = b_high[lane], gt = b_g2[lane];
#pragma unroll
        for (int jj = 0; jj < 8; jj++) {
            ip = fmaf(xms[w][jj], w_high[jj * HOR_ + lane], ip);
            gt = fmaf(sgs[w][jj], w_g2[jj * HOR_ + lane], gt);
        }
        float gate = 1.f / (1.f + __expf(-gt));
        float prog = last_step[g] * __expf(-0.1f * (float)(lane + 1));
        out[(size_t)g * HOR_ + lane] = gate * ip + (1.f - gate) * prog;
    }
}

extern "C" void kernel_launch(void* const* d_in, const int* in_sizes, int n_in,
                              void* d_out, int out_size, void* d_ws, size_t ws_size,
                              hipStream_t stream) {
    const float* x        = (const float*)d_in[0];
    const int*   adj      = (const int*)d_in[1];
    const float* last_step= (const float*)d_in[2];
    const float* loc_emb  = (const float*)d_in[3];
    const float* W_gat    = (const float*)d_in[4];
    const float* a_src    = (const float*)d_in[5];
    const float* a_dst    = (const float*)d_in[6];
    const float* ln_gat_g = (const float*)d_in[7];
    const float* ln_gat_b = (const float*)d_in[8];
    const float* ln_g     = (const float*)d_in[9];
    const float* ln_b     = (const float*)d_in[10];
    const float* w_low    = (const float*)d_in[11];
    const float* b_low    = (const float*)d_in[12];
    const float* ln_bn_g  = (const float*)d_in[13];
    const float* ln_bn_b  = (const float*)d_in[14];
    const float* w_high   = (const float*)d_in[15];
    const float* b_high   = (const float*)d_in[16];
    const float* w_g1     = (const float*)d_in[17];
    const float* b_g1     = (const float*)d_in[18];
    const float* w_g2     = (const float*)d_in[19];
    const float* b_g2     = (const float*)d_in[20];
    float* out = (float*)d_out;

    float* ws = (float*)d_ws;
    float*        h_prime = ws;                                   // 2,048,000 f32
    __bf16*       WhT     = (__bf16*)(ws + 2048000);              // 32*32*2048 bf16
    float2*       Etab    = (float2*)(ws + 3096576);              // 64,000 float2
    float2*       Ftab    = (float2*)(ws + 3224576);              // 64,000 float2
    unsigned int* adjp    = (unsigned int*)(ws + 3352576);        // 128,000 u32
    __bf16*       Wpk     = (__bf16*)(ws + 3480576);              // 2 x 20,480 bf16

    hipLaunchKernelGGL(k_pack, dim3(500),     dim3(256), 0, stream, adj, adjp, W_gat, Wpk);
    hipLaunchKernelGGL(k_wh,   dim3(500),     dim3(256), 0, stream, x, loc_emb, Wpk,
                       a_src, a_dst, WhT, Etab, Ftab);
    hipLaunchKernelGGL(k_attn, dim3(16, 32),  dim3(256), 0, stream, WhT, Etab, Ftab, adjp, h_prime);
    hipLaunchKernelGGL(k_head, dim3(4000),    dim3(256), 0, stream, h_prime, x, last_step,
                       ln_gat_g, ln_gat_b, ln_g, ln_b, w_low, b_low, ln_bn_g, ln_bn_b,
                       w_high, b_high, w_g1, b_g1, w_g2, b_g2, out);
}

// Round 7
// 184.392 us; speedup vs baseline: 1.0854x; 1.0854x over previous
//
#include <hip/hip_runtime.h>
#include <hip/hip_bf16.h>

#define B_      8
#define N_      2000
#define H_      128
#define HEADS_  4
#define INF_    160
#define DH_     32
#define BN_     8
#define HOR_    24
#define ALPHA_  0.2f
#define EPS_    1e-5f
#define LOG2E_  1.4426950408889634f

typedef __bf16 bf16x4 __attribute__((ext_vector_type(4)));
typedef __bf16 bf16x8 __attribute__((ext_vector_type(8)));
typedef float  f32x16 __attribute__((ext_vector_type(16)));
typedef float  f32x2  __attribute__((ext_vector_type(2)));

__device__ __forceinline__ float wredsum(float v) {
#pragma unroll
    for (int m = 1; m <= 32; m <<= 1) v += __shfl_xor(v, m, 64);
    return v;
}

// ---------------- Kernel P: adjacency bitmasks (ballot) + W_gat pack (blocks<80) ------
__global__ __launch_bounds__(256) void k_pack(const int* __restrict__ adj,
                                              unsigned int* __restrict__ adjp,
                                              const float* __restrict__ W_gat,
                                              __bf16* __restrict__ Wpk) {
    int t = threadIdx.x;
    if (blockIdx.x < 80) {                      // fused wprep: 80*256 = 20480 elems
        int idx = blockIdx.x * 256 + t;
        int h = idx / 5120, rem = idx % 5120;
        int s = rem / 512, q = rem % 512;
        int l = q >> 3, j = q & 7;
        int k = s * 16 + (l >> 5) * 8 + j;
        int o = l & 31;
        float v = W_gat[(h * INF_ + k) * 32 + o];
        __bf16 hi = (__bf16)v;
        Wpk[idx] = hi;
        Wpk[idx + 20480] = (__bf16)(v - (float)hi);
    }
    int lane = t & 63, w = t >> 6;
    int n = blockIdx.x * 4 + w;                 // 500 blocks x 4 waves = 2000 rows
    const int* row = adj + (size_t)n * N_;
#pragma unroll 4
    for (int it = 0; it < 32; it++) {
        int base = it * 64 + lane;
        int pred = (base < N_) ? (row[base] != 0) : 0;
        unsigned long long mask = __ballot(pred);
        if (lane == 0) {
            adjp[n * 64 + it * 2]     = (unsigned int)mask;
            adjp[n * 64 + it * 2 + 1] = (unsigned int)(mask >> 32);
        }
    }
}

// ---------------- Kernel WH: split-bf16 MFMA projection, fused ssd/ef + transpose -----
__global__ __launch_bounds__(256) void k_wh(const float* __restrict__ x,
                                            const float* __restrict__ loc_emb,
                                            const __bf16* __restrict__ Wpk,
                                            const float* __restrict__ a_src,
                                            const float* __restrict__ a_dst,
                                            __bf16* __restrict__ WhT,
                                            float2* __restrict__ Etab,
                                            float2* __restrict__ Ftab) {
    __shared__ __bf16 xhi[32][164];
    __shared__ __bf16 xlo[32][164];              // reused as transpose buffer later
    int t = threadIdx.x;
    int g0 = blockIdx.x * 32;
#pragma unroll
    for (int it = 0; it < 5; it++) {
        int idx = it * 256 + t;
        int r = idx / 40, c4 = idx % 40;
        int i4 = c4 * 4;
        float4 v;
        if (i4 < H_) {
            v = *(const float4*)&x[(size_t)(g0 + r) * H_ + i4];
        } else {
            int n = (g0 + r) % N_;
            v = *(const float4*)&loc_emb[n * 32 + (i4 - H_)];
        }
        bf16x4 h4, l4;
        h4[0] = (__bf16)v.x; l4[0] = (__bf16)(v.x - (float)h4[0]);
        h4[1] = (__bf16)v.y; l4[1] = (__bf16)(v.y - (float)h4[1]);
        h4[2] = (__bf16)v.z; l4[2] = (__bf16)(v.z - (float)h4[2]);
        h4[3] = (__bf16)v.w; l4[3] = (__bf16)(v.w - (float)h4[3]);
        *(bf16x4*)&xhi[r][i4] = h4;
        *(bf16x4*)&xlo[r][i4] = l4;
    }
    __syncthreads();

    int lane = t & 63, w = t >> 6;               // w = head
    int ln = lane & 31, grp = lane >> 5;
    f32x16 acc;
#pragma unroll
    for (int r = 0; r < 16; r++) acc[r] = 0.0f;

    for (int s = 0; s < 10; s++) {
        int off = s * 16 + grp * 8;
        bf16x4 a0 = *(const bf16x4*)&xhi[ln][off];
        bf16x4 a1 = *(const bf16x4*)&xhi[ln][off + 4];
        bf16x4 c0 = *(const bf16x4*)&xlo[ln][off];
        bf16x4 c1 = *(const bf16x4*)&xlo[ln][off + 4];
        bf16x8 ahi, alo;
#pragma unroll
        for (int q = 0; q < 4; q++) {
            ahi[q] = a0[q]; ahi[q + 4] = a1[q];
            alo[q] = c0[q]; alo[q + 4] = c1[q];
        }
        const __bf16* wp = Wpk + ((w * 10 + s) * 64 + lane) * 8;
        bf16x8 bhi = *(const bf16x8*)wp;
        bf16x8 blo = *(const bf16x8*)(wp + 20480);
        acc = __builtin_amdgcn_mfma_f32_32x32x16_bf16(ahi, bhi, acc, 0, 0, 0);
        acc = __builtin_amdgcn_mfma_f32_32x32x16_bf16(ahi, blo, acc, 0, 0, 0);
        acc = __builtin_amdgcn_mfma_f32_32x32x16_bf16(alo, bhi, acc, 0, 0, 0);
    }

    // ---- fused s_src/s_dst: reduce acc over cols (32 lanes of each half) ----
    float as = a_src[w * 32 + ln];
    float ad = a_dst[w * 32 + ln];
#pragma unroll
    for (int r = 0; r < 16; r++) {
        float ssv = acc[r] * as;
        float sdv = acc[r] * ad;
#pragma unroll
        for (int m = 1; m <= 16; m <<= 1) {
            ssv += __shfl_xor(ssv, m, 64);
            sdv += __shfl_xor(sdv, m, 64);
        }
        if (ln == 0) {
            int nr = (r & 3) + 8 * (r >> 2) + 4 * grp;
            int g = g0 + nr;
            int b = g / N_, n = g - b * N_;
            size_t idx = (size_t)(b * HEADS_ + w) * N_ + n;
            float sl = ssv * LOG2E_, dl = sdv * LOG2E_;
            Etab[idx] = make_float2(exp2f(sl), exp2f(0.2f * sl));
            Ftab[idx] = make_float2(exp2f(dl), exp2f(0.2f * dl));
        }
    }

    // ---- fused transpose -> WhT[bh][o][m] (reuse xlo as scratch) ----
    __syncthreads();                             // all waves done reading xhi/xlo
    __bf16 (*T)[34] = (__bf16(*)[34])((char*)&xlo[0][0] + w * 2176);  // [32 o][34]
#pragma unroll
    for (int r = 0; r < 16; r++) {
        int nr = (r & 3) + 8 * (r >> 2) + 4 * grp;
        T[ln][nr] = (__bf16)acc[r];
    }
    __syncthreads();
#pragma unroll
    for (int half = 0; half < 2; half++) {
        int j = grp * 16 + half * 8;             // 8 local rows
        int g = g0 + j;
        int b = g / N_, n = g - b * N_;
        if (n <= N_ - 8) {                       // no batch crossing in chunk
            uint4 d;
            d.x = *(const unsigned int*)&T[ln][j];
            d.y = *(const unsigned int*)&T[ln][j + 2];
            d.z = *(const unsigned int*)&T[ln][j + 4];
            d.w = *(const unsigned int*)&T[ln][j + 6];
            *(uint4*)(WhT + ((size_t)(b * HEADS_ + w) * 32 + ln) * 2048 + n) = d;
        } else {
            for (int i = 0; i < 8; i++) {
                int gg = g + i; int b2 = gg / N_, n2 = gg - b2 * N_;
                WhT[((size_t)(b2 * HEADS_ + w) * 32 + ln) * 2048 + n2] = T[ln][j + i];
            }
        }
    }
}

// ---------------- Kernel B: masked attention, packed-math scores + dual MFMA ----------
// grid (63 tiles x 32 bh) x 256 thr. Tile = 32 rows; wave w owns m-quarter w.
// pv = max(e1*f1, e5*f5) masked via sign-smear AND; lsum via MFMA with B=ones.
// Combine in TWO rounds of 8 regs -> LDS 23.7 KB -> 6 blocks/CU.
__global__ __launch_bounds__(256, 4) void k_attn(const __bf16* __restrict__ WhT,
                                                 const float2* __restrict__ Etab,
                                                 const float2* __restrict__ Ftab,
                                                 const unsigned int* __restrict__ adjp,
                                                 float* __restrict__ h_prime) {
    __shared__ float2 fl[2048];                  // 16 KB (f1,f5) per m
    __shared__ float cmbA[3][64][9];             // 6.75 KB: half-acc partials
    __shared__ float cmb2[3][2][16];             // row-sum partials (384 B)

    int t = threadIdx.x;
    int tile = blockIdx.x;                       // 0..62
    int bh = blockIdx.y;                         // 0..31
    int w = t >> 6, lane = t & 63;
    int ln = lane & 31, grp = lane >> 5;

    {
        const float4* Fb4 = (const float4*)(Ftab + (size_t)bh * N_);
        float4* fl4 = (float4*)fl;
        for (int i = t; i < 1024; i += 256)
            fl4[i] = (i < 1000) ? Fb4[i] : make_float4(0.f, 0.f, 0.f, 0.f);
    }
    int row = tile * 32 + ln;
    int rclamp = min(row, N_ - 1);
    float2 ee = Etab[(size_t)bh * N_ + rclamp];
    f32x2 ee2 = {ee.x, ee.y};
    const unsigned int* arow = adjp + (size_t)rclamp * 64;
    const __bf16* bbase = WhT + ((size_t)bh * 32 + ln) * 2048;

    f32x16 acc, acc2;
#pragma unroll
    for (int r = 0; r < 16; r++) { acc[r] = 0.0f; acc2[r] = 0.0f; }
    bf16x8 ones;
#pragma unroll
    for (int q = 0; q < 8; q++) ones[q] = (__bf16)1.0f;

    __syncthreads();

    for (int ci = 0; ci < 8; ci++) {
        int c = w * 8 + ci;                      // 64-m chunk within my quarter
        int m0 = c * 64;
        uint2 aw = *(const uint2*)&arow[c * 2];
        bf16x8 bfr[4];
#pragma unroll
        for (int s = 0; s < 4; s++)
            bfr[s] = *(const bf16x8*)&bbase[m0 + s * 16 + grp * 8];
#pragma unroll
        for (int s = 0; s < 4; s++) {
            int mo = m0 + s * 16 + grp * 8;
            unsigned int word = (s < 2) ? aw.x : aw.y;
            unsigned int mbyte = (word >> ((s & 1) * 16 + grp * 8)) & 0xffu;
            const float4* flp = (const float4*)&fl[mo];
            unsigned int au[4];
#pragma unroll
            for (int p = 0; p < 4; p++) {
                float4 fq = flp[p];              // (f1,f5, f1',f5') broadcast read
                f32x2 pa = f32x2{fq.x, fq.y} * ee2;
                f32x2 pb = f32x2{fq.z, fq.w} * ee2;
                float p0 = fmaxf(pa.x, pa.y);
                float p1 = fmaxf(pb.x, pb.y);
                // sign-smear mask: bit -> 0/-1, f32 AND (exact +0 when masked)
                int sm0 = ((int)(mbyte << (31 - 2 * p))) >> 31;
                int sm1 = ((int)(mbyte << (30 - 2 * p))) >> 31;
                p0 = __int_as_float(__float_as_int(p0) & sm0);
                p1 = __int_as_float(__float_as_int(p1) & sm1);
                unsigned int d;
                asm("v_cvt_pk_bf16_f32 %0, %1, %2" : "=v"(d) : "v"(p0), "v"(p1));
                au[p] = d;
            }
            union { uint4 u; bf16x8 b; } cvt;
            cvt.u = make_uint4(au[0], au[1], au[2], au[3]);
            acc  = __builtin_amdgcn_mfma_f32_32x32x16_bf16(cvt.b, bfr[s], acc, 0, 0, 0);
            acc2 = __builtin_amdgcn_mfma_f32_32x32x16_bf16(cvt.b, ones,   acc2, 0, 0, 0);
        }
    }

    // ---- two-round combine: waves 1..3 dump 8 regs at a time, wave 0 sums ----
    __syncthreads();
    if (w > 0) {
#pragma unroll
        for (int r = 0; r < 8; r++) cmbA[w - 1][lane][r] = acc[r];
        if (ln == 0) {
#pragma unroll
            for (int r = 0; r < 16; r++) cmb2[w - 1][grp][r] = acc2[r];
        }
    }
    __syncthreads();
    if (w == 0) {
#pragma unroll
        for (int r = 0; r < 8; r++)
            acc[r] += cmbA[0][lane][r] + cmbA[1][lane][r] + cmbA[2][lane][r];
    }
    __syncthreads();
    if (w > 0) {
#pragma unroll
        for (int r = 8; r < 16; r++) cmbA[w - 1][lane][r - 8] = acc[r];
    }
    __syncthreads();
    if (w == 0) {
        int bq = bh >> 2, hh = bh & 3;
#pragma unroll
        for (int r = 0; r < 16; r++) {
            float a = acc[r];
            if (r >= 8)
                a += cmbA[0][lane][r - 8] + cmbA[1][lane][r - 8] + cmbA[2][lane][r - 8];
            float d = acc2[r] + cmb2[0][grp][r] + cmb2[1][grp][r] + cmb2[2][grp][r];
            int nr = (r & 3) + 8 * (r >> 2) + 4 * grp;
            int n = tile * 32 + nr;
            if (n < N_) {
                h_prime[((size_t)(bq * N_ + n)) * H_ + hh * 32 + ln] = a / d;
            }
        }
    }
}

// ---------------- Kernel C: LN + residual + LN + MLP head ----------------
__global__ __launch_bounds__(256) void k_head(const float* __restrict__ h_prime,
        const float* __restrict__ x, const float* __restrict__ last_step,
        const float* __restrict__ ln_gat_g, const float* __restrict__ ln_gat_b,
        const float* __restrict__ ln_g, const float* __restrict__ ln_b,
        const float* __restrict__ w_low, const float* __restrict__ b_low,
        const float* __restrict__ ln_bn_g, const float* __restrict__ ln_bn_b,
        const float* __restrict__ w_high, const float* __restrict__ b_high,
        const float* __restrict__ w_g1, const float* __restrict__ b_g1,
        const float* __restrict__ w_g2, const float* __restrict__ b_g2,
        float* __restrict__ out) {
    __shared__ float hsh[4][128];
    __shared__ float xms[4][8], sgs[4][8];
    int t = threadIdx.x;
    int w = t >> 6, lane = t & 63;
    int g = blockIdx.x * 4 + w;

    float2 hp = *(const float2*)&h_prime[(size_t)g * H_ + lane * 2];
    float2 xr = *(const float2*)&x[(size_t)g * H_ + lane * 2];

    float mean = wredsum(hp.x + hp.y) * (1.f / H_);
    float d0 = hp.x - mean, d1 = hp.y - mean;
    float var = wredsum(d0 * d0 + d1 * d1) * (1.f / H_);
    float rs = rsqrtf(var + EPS_);
    float2 gg = *(const float2*)&ln_gat_g[lane * 2];
    float2 gb = *(const float2*)&ln_gat_b[lane * 2];
    float a0 = d0 * rs * gg.x + gb.x + xr.x;
    float a1 = d1 * rs * gg.y + gb.y + xr.y;

    float mean2 = wredsum(a0 + a1) * (1.f / H_);
    float e0 = a0 - mean2, e1 = a1 - mean2;
    float var2 = wredsum(e0 * e0 + e1 * e1) * (1.f / H_);
    float rs2 = rsqrtf(var2 + EPS_);
    float2 g2 = *(const float2*)&ln_g[lane * 2];
    float2 b2 = *(const float2*)&ln_b[lane * 2];
    float h0 = e0 * rs2 * g2.x + b2.x;
    float h1 = e1 * rs2 * g2.y + b2.y;

    *(float2*)&hsh[w][2 * lane] = make_float2(h0, h1);
    __syncthreads();

    int j = lane & 7, i16 = lane >> 3;
    float xa = 0.f, ga = 0.f;
#pragma unroll
    for (int q = 0; q < 16; q++) {
        int qq = (q + 2 * i16) & 15;
        int i = i16 * 16 + qq;
        float hv = hsh[w][i];
        xa = fmaf(hv, w_low[i * BN_ + j], xa);
        ga = fmaf(hv, w_g1[i * BN_ + j], ga);
    }
#pragma unroll
    for (int m = 8; m <= 32; m <<= 1) {
        xa += __shfl_xor(xa, m, 64);
        ga += __shfl_xor(ga, m, 64);
    }
    xa += b_low[j];

    float mb = xa;
#pragma unroll
    for (int m = 1; m <= 4; m <<= 1) mb += __shfl_xor(mb, m, 64);
    mb *= (1.f / BN_);
    float db = xa - mb;
    float vb = db * db;
#pragma unroll
    for (int m = 1; m <= 4; m <<= 1) vb += __shfl_xor(vb, m, 64);
    vb *= (1.f / BN_);
    float rb = rsqrtf(vb + EPS_);
    float v = db * rb * ln_bn_g[j] + ln_bn_b[j];
    float xm = v / (1.f + __expf(-v));
    float u = ga + b_g1[j];
    float sg = u / (1.f + __expf(-u));
    if (lane < 8) { xms[w][lane] = xm; sgs[w][lane] = sg; }
    __syncthreads();

    if (lane < HOR_) {
        float ip = b_high[lane], gt = b_g2[lane];
#pragma unroll
        for (int jj = 0; jj < 8; jj++) {
            ip = fmaf(xms[w][jj], w_high[jj * HOR_ + lane], ip);
            gt = fmaf(sgs[w][jj], w_g2[jj * HOR_ + lane], gt);
        }
        float gate = 1.f / (1.f + __expf(-gt));
        float prog = last_step[g] * __expf(-0.1f * (float)(lane + 1));
        out[(size_t)g * HOR_ + lane] = gate * ip + (1.f - gate) * prog;
    }
}

extern "C" void kernel_launch(void* const* d_in, const int* in_sizes, int n_in,
                              void* d_out, int out_size, void* d_ws, size_t ws_size,
                              hipStream_t stream) {
    const float* x        = (const float*)d_in[0];
    const int*   adj      = (const int*)d_in[1];
    const float* last_step= (const float*)d_in[2];
    const float* loc_emb  = (const float*)d_in[3];
    const float* W_gat    = (const float*)d_in[4];
    const float* a_src    = (const float*)d_in[5];
    const float* a_dst    = (const float*)d_in[6];
    const float* ln_gat_g = (const float*)d_in[7];
    const float* ln_gat_b = (const float*)d_in[8];
    const float* ln_g     = (const float*)d_in[9];
    const float* ln_b     = (const float*)d_in[10];
    const float* w_low    = (const float*)d_in[11];
    const float* b_low    = (const float*)d_in[12];
    const float* ln_bn_g  = (const float*)d_in[13];
    const float* ln_bn_b  = (const float*)d_in[14];
    const float* w_high   = (const float*)d_in[15];
    const float* b_high   = (const float*)d_in[16];
    const float* w_g1     = (const float*)d_in[17];
    const float* b_g1     = (const float*)d_in[18];
    const float* w_g2     = (const float*)d_in[19];
    const float* b_g2     = (const float*)d_in[20];
    float* out = (float*)d_out;

    float* ws = (float*)d_ws;
    float*        h_prime = ws;                                   // 2,048,000 f32
    __bf16*       WhT     = (__bf16*)(ws + 2048000);              // 32*32*2048 bf16
    float2*       Etab    = (float2*)(ws + 3096576);              // 64,000 float2
    float2*       Ftab    = (float2*)(ws + 3224576);              // 64,000 float2
    unsigned int* adjp    = (unsigned int*)(ws + 3352576);        // 128,000 u32
    __bf16*       Wpk     = (__bf16*)(ws + 3480576);              // 2 x 20,480 bf16

    hipLaunchKernelGGL(k_pack, dim3(500),     dim3(256), 0, stream, adj, adjp, W_gat, Wpk);
    hipLaunchKernelGGL(k_wh,   dim3(500),     dim3(256), 0, stream, x, loc_emb, Wpk,
                       a_src, a_dst, WhT, Etab, Ftab);
    hipLaunchKernelGGL(k_attn, dim3(63, 32),  dim3(256), 0, stream, WhT, Etab, Ftab, adjp, h_prime);
    hipLaunchKernelGGL(k_head, dim3(4000),    dim3(256), 0, stream, h_prime, x, last_step,
                       ln_gat_g, ln_gat_b, ln_g, ln_b, w_low, b_low, ln_bn_g, ln_bn_b,
                       w_high, b_high, w_g1, b_g1, w_g2, b_g2, out);
}